// Round 2
// baseline (25.068 us; speedup 1.0000x reference)
//
#include <hip/hip_runtime.h>

// Soft polygon rasterization (mode=mask), B=128, N=64, W=H=64.
// Two-kernel scheme:
//   prep_kernel: bake per-edge records (8 floats, 32B) into d_ws table.
//   softpoly_kernel: edge records loaded via wave-UNIFORM pointer -> s_load
//     (SGPR broadcast, no LDS, no __syncthreads). Parity via __ballot + s_xor
//     (scalar pipe). 4 px/thread in-row -> float4 store.

__global__ void prep_kernel(const float* __restrict__ verts,
                            float* __restrict__ tbl) {
    const int b = blockIdx.x;
    const int n = threadIdx.x;  // 0..63
    const float2* vp = (const float2*)verts + (b << 6);
    float2 a = vp[n];
    float2 c = vp[(n + 1) & 63];
    float dx = c.x - a.x, dy = c.y - a.y;
    float dd = fmaxf(fmaf(dx, dx, dy * dy), 1e-12f);
    float4* o = (float4*)tbl + (((b << 6) + n) << 1);
    o[0] = make_float4(a.x, a.y, dx, dy);
    o[1] = make_float4(1.0f / dd, c.y, dx / dy, 0.0f);  // dx/dy inf/nan ok: guarded by cond
}

// per-edge macro: E0 = (ax, ay, dx, dy), E1 = (1/dd, by, dx/dy, -)
#define EDGE(E0, E1, D2)                                          \
    {                                                             \
        float pay   = py - E0.y;                                  \
        float paydy = pay * E0.w;                                 \
        float pax0  = px0 - E0.x;                                 \
        bool  cond  = (E0.y > py) != (E1.y > py);                 \
        float xma   = cond ? pay * E1.z : -3.0e38f;               \
        _Pragma("unroll")                                         \
        for (int k = 0; k < 4; ++k) {                             \
            float pax = pax0 + (float)k;                          \
            float t   = fmaf(pax, E0.z, paydy) * E1.x;            \
            t         = fminf(fmaxf(t, 0.0f), 1.0f);              \
            float ex  = fmaf(-t, E0.z, pax);                      \
            float ey  = fmaf(-t, E0.w, pay);                      \
            D2[k]     = fmaf(ex, ex, ey * ey);                    \
            pm[k]    ^= __ballot(pax < xma);                      \
        }                                                         \
    }

__global__ __launch_bounds__(256) void softpoly_kernel(
    const float* __restrict__ tbl, float* __restrict__ out)
{
    const int tid = threadIdx.x;
    const int b   = blockIdx.x >> 2;

    // force wave-uniform table pointer so loads scalarize to s_load
    const float4* t4 = (const float4*)tbl + ((size_t)b << 7);  // 128 float4/batch
    {
        uint64_t v  = (uint64_t)t4;
        uint32_t lo = __builtin_amdgcn_readfirstlane((uint32_t)v);
        uint32_t hi = __builtin_amdgcn_readfirstlane((uint32_t)(v >> 32));
        t4 = (const float4*)(((uint64_t)hi << 32) | lo);
    }

    const int row = ((blockIdx.x & 3) << 4) + (tid >> 4);  // 0..63
    const float py  = (float)row;
    const float px0 = (float)((tid & 15) << 2);

    float md[4] = {1e30f, 1e30f, 1e30f, 1e30f};
    unsigned long long pm[4] = {0ull, 0ull, 0ull, 0ull};

    #pragma unroll 2
    for (int n = 0; n < 64; n += 2) {
        float4 A0 = t4[(n << 1) + 0];
        float4 A1 = t4[(n << 1) + 1];
        float4 B0 = t4[(n << 1) + 2];
        float4 B1 = t4[(n << 1) + 3];
        float d2a[4], d2b[4];
        EDGE(A0, A1, d2a)
        EDGE(B0, B1, d2b)
        #pragma unroll
        for (int k = 0; k < 4; ++k)
            md[k] = fminf(md[k], fminf(d2a[k], d2b[k]));  // -> v_min3_f32
    }

    const int lane = tid & 63;
    float4 r;
    float* rp = &r.x;
    #pragma unroll
    for (int k = 0; k < 4; ++k) {
        float s = ((pm[k] >> lane) & 1ull) ? 10.0f : -10.0f;  // sign/inv_smoothness
        rp[k] = 1.0f / (1.0f + __expf(-s * md[k]));
    }
    ((float4*)out)[((size_t)b << 10) + (row << 4) + (tid & 15)] = r;
}

extern "C" void kernel_launch(void* const* d_in, const int* in_sizes, int n_in,
                              void* d_out, int out_size, void* d_ws, size_t ws_size,
                              hipStream_t stream) {
    const float* verts = (const float*)d_in[0];
    float* out = (float*)d_out;
    float* tbl = (float*)d_ws;           // 128*64*8 floats = 256 KB
    const int B = out_size >> 12;        // 64*64 px per image
    prep_kernel<<<dim3(B), dim3(64), 0, stream>>>(verts, tbl);
    softpoly_kernel<<<dim3(B * 4), dim3(256), 0, stream>>>(tbl, out);
}

// Round 3
// 16.061 us; speedup vs baseline: 1.5608x; 1.5608x over previous
//
#include <hip/hip_runtime.h>

// Soft polygon rasterization (mode=mask), B=128, N=64, W=H=64.
// Single launch. Block = 256 threads = one batch x 8-row chunk (512 px,
// 2 consecutive x-pixels per thread -> float2 store). grid = B*8 = 1024
// blocks = 4096 waves = 4 waves/SIMD (latency hiding; R1 had only 2).
// Threads 0..63 build per-edge records in LDS (one barrier); inner loop
// reads them as same-address broadcast ds_read_b128 (conflict-free).
// Records premultiplied: (ax,ay,dx,dy) and (dx/dd, dy/dd, dx/dy, by)
// so per-pixel work is: pax add, t fma+med3, ex fma, ey fma, d2 mul+fma,
// crossing v_cmp (+scalar-pipe mask and/xor via __ballot).

#define EDGE(E0, E1, DA, DB)                                       \
    {                                                              \
        float pay  = py - E0.y;                                    \
        float pdyr = pay * E1.y;                                   \
        float xint = fmaf(pay, E1.z, E0.x);                        \
        bool  cond = (E0.y > py) != (E1.w > py);                   \
        float paxa = px0 - E0.x;                                   \
        float paxb = paxa + 1.0f;                                  \
        float ta = fminf(fmaxf(fmaf(paxa, E1.x, pdyr), 0.0f), 1.0f); \
        float tb = fminf(fmaxf(fmaf(paxb, E1.x, pdyr), 0.0f), 1.0f); \
        float exa = fmaf(-ta, E0.z, paxa);                         \
        float eya = fmaf(-ta, E0.w, pay);                          \
        float exb = fmaf(-tb, E0.z, paxb);                         \
        float eyb = fmaf(-tb, E0.w, pay);                          \
        DA = fmaf(exa, exa, eya * eya);                            \
        DB = fmaf(exb, exb, eyb * eyb);                            \
        pm0 ^= __ballot(cond && (px0 < xint));                     \
        pm1 ^= __ballot(cond && (px1 < xint));                     \
    }

__global__ __launch_bounds__(256, 4) void softpoly_kernel(
    const float* __restrict__ verts, float* __restrict__ out)
{
    __shared__ float4 e0[64];  // ax, ay, dx, dy
    __shared__ float4 e1[64];  // dx/dd, dy/dd, dx/dy, by

    const int tid = threadIdx.x;
    const int b   = blockIdx.x >> 3;

    if (tid < 64) {
        const float2* vp = (const float2*)(verts + (b << 7));
        float2 a = vp[tid];
        float2 c = vp[(tid + 1) & 63];
        float dx = c.x - a.x, dy = c.y - a.y;
        float dd = fmaxf(fmaf(dx, dx, dy * dy), 1e-12f);
        float rdd = 1.0f / dd;
        e0[tid] = make_float4(a.x, a.y, dx, dy);
        e1[tid] = make_float4(dx * rdd, dy * rdd, dx / dy, c.y);
    }
    __syncthreads();

    const int row = ((blockIdx.x & 7) << 3) + (tid >> 5);  // 0..63
    const float py  = (float)row;
    const float px0 = (float)((tid & 31) << 1);
    const float px1 = px0 + 1.0f;

    float md0 = 1e30f, md1 = 1e30f;
    unsigned long long pm0 = 0ull, pm1 = 0ull;

    #pragma unroll 2
    for (int n = 0; n < 64; n += 2) {
        const float4 A0 = e0[n],     A1 = e1[n];
        const float4 B0 = e0[n + 1], B1 = e1[n + 1];
        float dA0, dA1, dB0, dB1;
        EDGE(A0, A1, dA0, dA1)
        EDGE(B0, B1, dB0, dB1)
        md0 = fminf(md0, fminf(dA0, dB0));  // -> v_min3_f32
        md1 = fminf(md1, fminf(dA1, dB1));
    }

    const int lane = tid & 63;
    const float s0 = ((pm0 >> lane) & 1ull) ? 10.0f : -10.0f;
    const float s1 = ((pm1 >> lane) & 1ull) ? 10.0f : -10.0f;
    float2 r;
    r.x = 1.0f / (1.0f + __expf(-s0 * md0));
    r.y = 1.0f / (1.0f + __expf(-s1 * md1));
    ((float2*)out)[(((b << 6) + row) << 5) + (tid & 31)] = r;
}

extern "C" void kernel_launch(void* const* d_in, const int* in_sizes, int n_in,
                              void* d_out, int out_size, void* d_ws, size_t ws_size,
                              hipStream_t stream) {
    const float* verts = (const float*)d_in[0];
    float* out = (float*)d_out;
    const int B = out_size >> 12;  // 64*64 px per image
    softpoly_kernel<<<dim3(B * 8), dim3(256), 0, stream>>>(verts, out);
}